// Round 1
// baseline (3086.356 us; speedup 1.0000x reference)
//
#include <hip/hip_runtime.h>

#define NHW 15
#define NWIN (8 * NHW * NHW)  // 1800

typedef __bf16 bf16x8 __attribute__((ext_vector_type(8)));
typedef float f32x4 __attribute__((ext_vector_type(4)));

__device__ __forceinline__ unsigned short f2bf(float f) {
  unsigned x = __float_as_uint(f);
  unsigned r = ((x >> 16) & 1u) + 0x7fffu;  // round-to-nearest-even
  x += r;
  return (unsigned short)(x >> 16);
}

// Convert w_qkv (1536x512) and w_out (512x512) f32 -> bf16 into workspace.
__global__ void convert_weights(const float* __restrict__ wq,
                                const float* __restrict__ wo,
                                unsigned short* __restrict__ dst) {
  const int NQ = 786432;  // 1536*512
  int i = (blockIdx.x * 256 + threadIdx.x) * 4;
  float4 v;
  if (i < NQ) v = *(const float4*)(wq + i);
  else        v = *(const float4*)(wo + (i - NQ));
  ushort4 o;
  o.x = f2bf(v.x); o.y = f2bf(v.y); o.z = f2bf(v.z); o.w = f2bf(v.w);
  *(ushort4*)(dst + i) = o;
}

__launch_bounds__(512, 2)
__global__ void swin_kernel(const float* __restrict__ x,
                            const float* __restrict__ b_out,
                            const unsigned short* __restrict__ wq_all,  // [1536][512] bf16
                            const unsigned short* __restrict__ wo,      // [512][512]  bf16
                            float* __restrict__ res) {
  // region0: xv[64][520] bf16 (66560B), overlaid later by 8 x 10240B per-wave scratch
  __shared__ __align__(16) unsigned short lds0[40960];   // 81920 B
  // region1: att_out[64][520] bf16
  __shared__ __align__(16) unsigned short lds1[64 * 520];  // 66560 B

  const int tid  = threadIdx.x;
  const int wave = tid >> 6;
  const int ln   = tid & 63;
  const int rowa = ln & 15;   // A-frag row / B-frag col within 16-tile
  const int kgrp = ln >> 4;   // 0..3 : k-subgroup (8 elems each)
  const int rbase = kgrp * 4; // C/D-layout row base within 16-tile

  const int bid = blockIdx.x;
  const int b  = bid / (NHW * NHW);
  const int rm = bid % (NHW * NHW);
  const int n  = rm / NHW;
  const int w  = rm % NHW;
  const int i0 = n * 4, j0 = w * 4;

  // ---------------- stage scrambled patch xv (bf16) ----------------
  // xv[l][c] = x[b, i0 + (c%64)/8, j0 + (c%64)%8, l*8 + c/64]
  for (int r = 0; r < 8; ++r) {
    const float* rowp = x + (((size_t)(b * 64 + i0 + r)) * 64 + j0) * 512;
    #pragma unroll
    for (int it = 0; it < 2; ++it) {
      int idx4 = (it * 512 + tid) * 4;      // 0..4092, element in (kj, ch) run
      float4 v4 = *(const float4*)(rowp + idx4);
      int kj  = idx4 >> 9;
      int ch0 = idx4 & 511;
      float vv[4] = {v4.x, v4.y, v4.z, v4.w};
      #pragma unroll
      for (int e = 0; e < 4; ++e) {
        int ch = ch0 + e;
        int l = ch >> 3;
        int c = ((ch & 7) << 6) + (r << 3) + kj;
        lds0[l * 520 + c] = f2bf(vv[e]);
      }
    }
  }
  __syncthreads();

  // ---------------- GEMM1: qkv = xv @ W^T (3 steps; wave owns head `wave`) ----
  unsigned qp[4][4][2], kp[4][4][2], vp[4][4][2];  // packed bf16 pairs (rows 2p,2p+1)
  {
    auto step = [&](int O, unsigned (&dst)[4][4][2]) {
      f32x4 acc[4][4];
      #pragma unroll
      for (int i = 0; i < 4; ++i)
        #pragma unroll
        for (int j = 0; j < 4; ++j) acc[i][j] = (f32x4){0.f, 0.f, 0.f, 0.f};
      for (int ks = 0; ks < 16; ++ks) {
        bf16x8 a[4];
        #pragma unroll
        for (int mt = 0; mt < 4; ++mt)
          a[mt] = *(const bf16x8*)(lds0 + (mt * 16 + rowa) * 520 + ks * 32 + kgrp * 8);
        #pragma unroll
        for (int nt = 0; nt < 4; ++nt) {
          bf16x8 bfr = *(const bf16x8*)(wq_all + (size_t)(O + nt * 16 + rowa) * 512 + ks * 32 + kgrp * 8);
          #pragma unroll
          for (int mt = 0; mt < 4; ++mt)
            acc[mt][nt] = __builtin_amdgcn_mfma_f32_16x16x32_bf16(a[mt], bfr, acc[mt][nt], 0, 0, 0);
        }
      }
      #pragma unroll
      for (int mt = 0; mt < 4; ++mt)
        #pragma unroll
        for (int nt = 0; nt < 4; ++nt)
          #pragma unroll
          for (int p = 0; p < 2; ++p)
            dst[mt][nt][p] = (unsigned)f2bf(acc[mt][nt][2 * p]) |
                             ((unsigned)f2bf(acc[mt][nt][2 * p + 1]) << 16);
    };
    step(wave * 64,        qp);
    step(512 + wave * 64,  kp);
    step(1024 + wave * 64, vp);
  }
  __syncthreads();  // xv dead; per-wave scratch may overlay region0

  // ---------------- attention: head = wave, all private -------------
  unsigned short* qsc = lds0 + wave * 5120;  // 64 x 40 bf16 (80B rows, 16B aligned)
  unsigned short* ksc = qsc + 2560;

  f32x4 dt_[4][4];
  #pragma unroll
  for (int i = 0; i < 4; ++i)
    #pragma unroll
    for (int j = 0; j < 4; ++j) dt_[i][j] = (f32x4){0.f, 0.f, 0.f, 0.f};

  #pragma unroll
  for (int h2 = 0; h2 < 2; ++h2) {  // d-half of K=64
    #pragma unroll
    for (int mt = 0; mt < 4; ++mt)
      #pragma unroll
      for (int cc = 0; cc < 2; ++cc) {
        int ct = 2 * h2 + cc;
        #pragma unroll
        for (int p = 0; p < 2; ++p) {
          unsigned uq = qp[mt][ct][p];
          unsigned uk = kp[mt][ct][p];
          int rr = mt * 16 + rbase + 2 * p;
          int dd = cc * 16 + rowa;
          qsc[rr * 40 + dd]       = (unsigned short)uq;
          qsc[(rr + 1) * 40 + dd] = (unsigned short)(uq >> 16);
          ksc[rr * 40 + dd]       = (unsigned short)uk;
          ksc[(rr + 1) * 40 + dd] = (unsigned short)(uk >> 16);
        }
      }
    bf16x8 aq[4];
    #pragma unroll
    for (int mt = 0; mt < 4; ++mt)
      aq[mt] = *(const bf16x8*)(qsc + (mt * 16 + rowa) * 40 + kgrp * 8);
    #pragma unroll
    for (int nt = 0; nt < 4; ++nt) {
      bf16x8 bk = *(const bf16x8*)(ksc + (nt * 16 + rowa) * 40 + kgrp * 8);
      #pragma unroll
      for (int mt = 0; mt < 4; ++mt)
        dt_[mt][nt] = __builtin_amdgcn_mfma_f32_16x16x32_bf16(aq[mt], bk, dt_[mt][nt], 0, 0, 0);
    }
  }

  // softmax (scale = hd^-0.5 = 1/8); per-row constant bias drops out exactly
  const float SC = 0.125f * 1.44269504088896f;
  float rsum[4][4];
  #pragma unroll
  for (int mt = 0; mt < 4; ++mt)
    #pragma unroll
    for (int j = 0; j < 4; ++j) {
      float m = dt_[mt][0][j];
      #pragma unroll
      for (int nt = 1; nt < 4; ++nt) m = fmaxf(m, dt_[mt][nt][j]);
      #pragma unroll
      for (int s = 1; s < 16; s <<= 1) m = fmaxf(m, __shfl_xor(m, s, 64));
      float sum = 0.f;
      #pragma unroll
      for (int nt = 0; nt < 4; ++nt) {
        float p = exp2f((dt_[mt][nt][j] - m) * SC);
        dt_[mt][nt][j] = p;
        sum += p;
      }
      #pragma unroll
      for (int s = 1; s < 16; s <<= 1) sum += __shfl_xor(sum, s, 64);
      rsum[mt][j] = sum;
    }

  // PV: out_h = P @ v  (stage P and v^T per m-half; scratch reuse, same-wave only)
  unsigned short* Psc  = qsc;
  unsigned short* vTsc = ksc;
  f32x4 oat[4][4];
  #pragma unroll
  for (int i = 0; i < 4; ++i)
    #pragma unroll
    for (int j = 0; j < 4; ++j) oat[i][j] = (f32x4){0.f, 0.f, 0.f, 0.f};

  #pragma unroll
  for (int mh = 0; mh < 2; ++mh) {
    #pragma unroll
    for (int mt = 0; mt < 4; ++mt)
      #pragma unroll
      for (int cc = 0; cc < 2; ++cc) {
        int ct = 2 * mh + cc;
        #pragma unroll
        for (int j = 0; j < 4; ++j)
          Psc[(mt * 16 + rbase + j) * 40 + cc * 16 + rowa] = f2bf(dt_[mt][ct][j]);
      }
    #pragma unroll
    for (int mm = 0; mm < 2; ++mm) {
      int mtm = 2 * mh + mm;
      #pragma unroll
      for (int ct = 0; ct < 4; ++ct)
        #pragma unroll
        for (int p = 0; p < 2; ++p) {
          unsigned u = vp[mtm][ct][p];
          int m_ = mm * 16 + rbase + 2 * p;
          int d  = ct * 16 + rowa;
          *(unsigned*)(vTsc + d * 40 + m_) = u;  // two adjacent m' -> one b32 write
        }
    }
    bf16x8 ap[4];
    #pragma unroll
    for (int mt = 0; mt < 4; ++mt)
      ap[mt] = *(const bf16x8*)(Psc + (mt * 16 + rowa) * 40 + kgrp * 8);
    #pragma unroll
    for (int dtt = 0; dtt < 4; ++dtt) {
      bf16x8 bv = *(const bf16x8*)(vTsc + (dtt * 16 + rowa) * 40 + kgrp * 8);
      #pragma unroll
      for (int mt = 0; mt < 4; ++mt)
        oat[mt][dtt] = __builtin_amdgcn_mfma_f32_16x16x32_bf16(ap[mt], bv, oat[mt][dtt], 0, 0, 0);
    }
  }

  // normalize + stage att_out (cols [wave*64, wave*64+64))
  #pragma unroll
  for (int mt = 0; mt < 4; ++mt)
    #pragma unroll
    for (int j = 0; j < 4; ++j) {
      float inv = 1.f / rsum[mt][j];
      #pragma unroll
      for (int dtt = 0; dtt < 4; ++dtt)
        lds1[(mt * 16 + rbase + j) * 520 + wave * 64 + dtt * 16 + rowa] =
            f2bf(oat[mt][dtt][j] * inv);
    }
  __syncthreads();

  // ---------------- GEMM2: out2 = att_out @ w_out^T + b_out ----------
  f32x4 a2[4][4];
  #pragma unroll
  for (int i = 0; i < 4; ++i)
    #pragma unroll
    for (int j = 0; j < 4; ++j) a2[i][j] = (f32x4){0.f, 0.f, 0.f, 0.f};
  for (int ks = 0; ks < 16; ++ks) {
    bf16x8 a[4];
    #pragma unroll
    for (int mt = 0; mt < 4; ++mt)
      a[mt] = *(const bf16x8*)(lds1 + (mt * 16 + rowa) * 520 + ks * 32 + kgrp * 8);
    #pragma unroll
    for (int nt = 0; nt < 4; ++nt) {
      bf16x8 bw = *(const bf16x8*)(wo + (size_t)(wave * 64 + nt * 16 + rowa) * 512 + ks * 32 + kgrp * 8);
      #pragma unroll
      for (int mt = 0; mt < 4; ++mt)
        a2[mt][nt] = __builtin_amdgcn_mfma_f32_16x16x32_bf16(a[mt], bw, a2[mt][nt], 0, 0, 0);
    }
  }

  // epilogue: bias + inverse scramble + overlapping scatter-add
  float bias[4];
  #pragma unroll
  for (int nt = 0; nt < 4; ++nt) bias[nt] = b_out[wave * 64 + nt * 16 + rowa];
  #pragma unroll
  for (int mt = 0; mt < 4; ++mt)
    #pragma unroll
    for (int j = 0; j < 4; ++j) {
      int l = mt * 16 + rbase + j;
      #pragma unroll
      for (int nt = 0; nt < 4; ++nt) {
        int o = wave * 64 + nt * 16 + rowa;
        float val = a2[mt][nt][j] + bias[nt];
        int ch = l * 8 + (o >> 6);
        int p  = o & 63;
        int gh = i0 + (p >> 3);
        int gw = j0 + (p & 7);
        atomicAdd(res + (((size_t)(b * 64 + gh)) * 64 + gw) * 512 + ch, val);
      }
    }
}

extern "C" void kernel_launch(void* const* d_in, const int* in_sizes, int n_in,
                              void* d_out, int out_size, void* d_ws, size_t ws_size,
                              hipStream_t stream) {
  const float* x      = (const float*)d_in[0];
  const float* w_qkv  = (const float*)d_in[1];
  const float* w_out  = (const float*)d_in[2];
  const float* b_out  = (const float*)d_in[3];
  // d_in[4], d_in[5] (rel_h, rel_w): per-query-row constant bias is softmax-invariant -> unused
  float* res = (float*)d_out;
  unsigned short* wbf = (unsigned short*)d_ws;  // [0,1.5MB) w_qkv bf16, then w_out bf16

  hipMemsetAsync(d_out, 0, (size_t)out_size * sizeof(float), stream);
  convert_weights<<<1024, 256, 0, stream>>>(w_qkv, w_out, wbf);
  swin_kernel<<<NWIN, 512, 0, stream>>>(x, b_out, wbf, wbf + 786432, res);
}

// Round 2
// 2826.277 us; speedup vs baseline: 1.0920x; 1.0920x over previous
//
#include <hip/hip_runtime.h>

#define NHW 15
#define NWIN (8 * NHW * NHW)  // 1800

typedef __bf16 bf16x8 __attribute__((ext_vector_type(8)));
typedef float f32x4 __attribute__((ext_vector_type(4)));

__device__ __forceinline__ unsigned short f2bf(float f) {
  unsigned x = __float_as_uint(f);
  unsigned r = ((x >> 16) & 1u) + 0x7fffu;  // round-to-nearest-even
  x += r;
  return (unsigned short)(x >> 16);
}

// Convert w_qkv (1536x512) and w_out (512x512) f32 -> bf16 into workspace.
__global__ void convert_weights(const float* __restrict__ wq,
                                const float* __restrict__ wo,
                                unsigned short* __restrict__ dst) {
  const int NQ = 786432;  // 1536*512
  int i = (blockIdx.x * 256 + threadIdx.x) * 4;
  float4 v;
  if (i < NQ) v = *(const float4*)(wq + i);
  else        v = *(const float4*)(wo + (i - NQ));
  ushort4 o;
  o.x = f2bf(v.x); o.y = f2bf(v.y); o.z = f2bf(v.z); o.w = f2bf(v.w);
  *(ushort4*)(dst + i) = o;
}

// Sum <=4 overlapping window contributions per output element.
// ws layout per window: [o(512)][l(64)] f32; value (l,o) goes to
// res[b, 4n+(p>>3), 4w+(p&7), l*8+(o>>6)] with p = o&63.
__launch_bounds__(256)
__global__ void gather_kernel(const float* __restrict__ wsf,
                              float* __restrict__ res) {
  int t  = blockIdx.x * 256 + threadIdx.x;  // [0, 4194304) float4s
  int ch4 = (t & 127) << 2;                 // 0..508 step 4
  int r1 = t >> 7;
  int gw = r1 & 63;
  int r2 = r1 >> 6;
  int gh = r2 & 63;
  int b  = r2 >> 6;
  int l   = ch4 >> 3;
  int c70 = ch4 & 7;  // 0 or 4
  int n_lo = (gh >= 8) ? ((gh - 4) >> 2) : 0;
  int n_hi = min(gh >> 2, NHW - 1);
  int w_lo = (gw >= 8) ? ((gw - 4) >> 2) : 0;
  int w_hi = min(gw >> 2, NHW - 1);
  float4 acc = {0.f, 0.f, 0.f, 0.f};
  for (int n = n_lo; n <= n_hi; ++n)
    for (int w = w_lo; w <= w_hi; ++w) {
      const float* base = wsf + ((size_t)((b * NHW + n) * NHW + w)) * 32768;
      int p   = (gh - 4 * n) * 8 + (gw - 4 * w);
      int off = p * 64 + l;
      acc.x += base[(c70 + 0) * 4096 + off];
      acc.y += base[(c70 + 1) * 4096 + off];
      acc.z += base[(c70 + 2) * 4096 + off];
      acc.w += base[(c70 + 3) * 4096 + off];
    }
  *(float4*)(res + ((size_t)t << 2)) = acc;
}

__launch_bounds__(512, 4)
__global__ void swin_kernel(const float* __restrict__ x,
                            const float* __restrict__ b_out,
                            const unsigned short* __restrict__ wq_all,  // [1536][512] bf16
                            const unsigned short* __restrict__ wo,      // [512][512]  bf16
                            float* __restrict__ res,
                            float* __restrict__ wsout,
                            int use_ws) {
  // single 80KiB region, time-shared:
  //   phase A: xv[64][520] bf16 (66560B)
  //   phase B: 8 x 10240B per-wave attention scratch
  //   phase C: att_out[64][520] bf16
  __shared__ __align__(16) unsigned short lds0[40960];  // 81920 B -> 2 blocks/CU

  const int tid  = threadIdx.x;
  const int wave = tid >> 6;
  const int ln   = tid & 63;
  const int rowa = ln & 15;   // A-frag row / B-frag col within 16-tile
  const int kgrp = ln >> 4;   // 0..3 : k-subgroup (8 elems each)
  const int rbase = kgrp * 4; // C/D-layout row base within 16-tile

  const int bid = blockIdx.x;
  const int b  = bid / (NHW * NHW);
  const int rm = bid % (NHW * NHW);
  const int n  = rm / NHW;
  const int w  = rm % NHW;
  const int i0 = n * 4, j0 = w * 4;

  // ---------------- stage scrambled patch xv (bf16) ----------------
  // xv[l][c] = x[b, i0 + (c%64)/8, j0 + (c%64)%8, l*8 + c/64]
  for (int r = 0; r < 8; ++r) {
    const float* rowp = x + (((size_t)(b * 64 + i0 + r)) * 64 + j0) * 512;
    #pragma unroll
    for (int it = 0; it < 2; ++it) {
      int idx4 = (it * 512 + tid) * 4;      // 0..4092, element in (kj, ch) run
      float4 v4 = *(const float4*)(rowp + idx4);
      int kj  = idx4 >> 9;
      int ch0 = idx4 & 511;
      float vv[4] = {v4.x, v4.y, v4.z, v4.w};
      #pragma unroll
      for (int e = 0; e < 4; ++e) {
        int ch = ch0 + e;
        int l = ch >> 3;
        int c = ((ch & 7) << 6) + (r << 3) + kj;
        lds0[l * 520 + c] = f2bf(vv[e]);
      }
    }
  }
  __syncthreads();

  // ---------------- GEMM1: qkv = xv @ W^T (3 steps; wave owns head `wave`) ----
  unsigned qp[4][4][2], kp[4][4][2], vp[4][4][2];  // packed bf16 pairs (rows 2p,2p+1)
  {
    auto step = [&](int O, unsigned (&dst)[4][4][2]) {
      f32x4 acc[4][4];
      #pragma unroll
      for (int i = 0; i < 4; ++i)
        #pragma unroll
        for (int j = 0; j < 4; ++j) acc[i][j] = (f32x4){0.f, 0.f, 0.f, 0.f};
      for (int ks = 0; ks < 16; ++ks) {
        bf16x8 a[4];
        #pragma unroll
        for (int mt = 0; mt < 4; ++mt)
          a[mt] = *(const bf16x8*)(lds0 + (mt * 16 + rowa) * 520 + ks * 32 + kgrp * 8);
        #pragma unroll
        for (int nt = 0; nt < 4; ++nt) {
          bf16x8 bfr = *(const bf16x8*)(wq_all + (size_t)(O + nt * 16 + rowa) * 512 + ks * 32 + kgrp * 8);
          #pragma unroll
          for (int mt = 0; mt < 4; ++mt)
            acc[mt][nt] = __builtin_amdgcn_mfma_f32_16x16x32_bf16(a[mt], bfr, acc[mt][nt], 0, 0, 0);
        }
      }
      #pragma unroll
      for (int mt = 0; mt < 4; ++mt)
        #pragma unroll
        for (int nt = 0; nt < 4; ++nt)
          #pragma unroll
          for (int p = 0; p < 2; ++p)
            dst[mt][nt][p] = (unsigned)f2bf(acc[mt][nt][2 * p]) |
                             ((unsigned)f2bf(acc[mt][nt][2 * p + 1]) << 16);
    };
    step(wave * 64,        qp);
    step(512 + wave * 64,  kp);
    step(1024 + wave * 64, vp);
  }
  __syncthreads();  // xv dead; per-wave scratch may overlay lds0

  // ---------------- attention: head = wave, all private -------------
  unsigned short* qsc = lds0 + wave * 5120;  // 64 x 40 bf16 rows (80B, 16B aligned)
  unsigned short* ksc = qsc + 2560;

  f32x4 dt_[4][4];
  #pragma unroll
  for (int i = 0; i < 4; ++i)
    #pragma unroll
    for (int j = 0; j < 4; ++j) dt_[i][j] = (f32x4){0.f, 0.f, 0.f, 0.f};

  #pragma unroll
  for (int h2 = 0; h2 < 2; ++h2) {  // d-half of K=64
    #pragma unroll
    for (int mt = 0; mt < 4; ++mt)
      #pragma unroll
      for (int cc = 0; cc < 2; ++cc) {
        int ct = 2 * h2 + cc;
        #pragma unroll
        for (int p = 0; p < 2; ++p) {
          unsigned uq = qp[mt][ct][p];
          unsigned uk = kp[mt][ct][p];
          int rr = mt * 16 + rbase + 2 * p;
          int dd = cc * 16 + rowa;
          qsc[rr * 40 + dd]       = (unsigned short)uq;
          qsc[(rr + 1) * 40 + dd] = (unsigned short)(uq >> 16);
          ksc[rr * 40 + dd]       = (unsigned short)uk;
          ksc[(rr + 1) * 40 + dd] = (unsigned short)(uk >> 16);
        }
      }
    bf16x8 aq[4];
    #pragma unroll
    for (int mt = 0; mt < 4; ++mt)
      aq[mt] = *(const bf16x8*)(qsc + (mt * 16 + rowa) * 40 + kgrp * 8);
    #pragma unroll
    for (int nt = 0; nt < 4; ++nt) {
      bf16x8 bk = *(const bf16x8*)(ksc + (nt * 16 + rowa) * 40 + kgrp * 8);
      #pragma unroll
      for (int mt = 0; mt < 4; ++mt)
        dt_[mt][nt] = __builtin_amdgcn_mfma_f32_16x16x32_bf16(aq[mt], bk, dt_[mt][nt], 0, 0, 0);
    }
  }

  // softmax (scale = hd^-0.5 = 1/8); per-row constant bias drops out exactly
  const float SC = 0.125f * 1.44269504088896f;
  float rsum[4][4];
  #pragma unroll
  for (int mt = 0; mt < 4; ++mt)
    #pragma unroll
    for (int j = 0; j < 4; ++j) {
      float m = dt_[mt][0][j];
      #pragma unroll
      for (int nt = 1; nt < 4; ++nt) m = fmaxf(m, dt_[mt][nt][j]);
      #pragma unroll
      for (int s = 1; s < 16; s <<= 1) m = fmaxf(m, __shfl_xor(m, s, 64));
      float sum = 0.f;
      #pragma unroll
      for (int nt = 0; nt < 4; ++nt) {
        float p = exp2f((dt_[mt][nt][j] - m) * SC);
        dt_[mt][nt][j] = p;
        sum += p;
      }
      #pragma unroll
      for (int s = 1; s < 16; s <<= 1) sum += __shfl_xor(sum, s, 64);
      rsum[mt][j] = sum;
    }

  // PV: out_h = P @ v  (stage P and v^T per m-half; same-wave scratch reuse)
  unsigned short* Psc  = qsc;
  unsigned short* vTsc = ksc;
  f32x4 oat[4][4];
  #pragma unroll
  for (int i = 0; i < 4; ++i)
    #pragma unroll
    for (int j = 0; j < 4; ++j) oat[i][j] = (f32x4){0.f, 0.f, 0.f, 0.f};

  #pragma unroll
  for (int mh = 0; mh < 2; ++mh) {
    #pragma unroll
    for (int mt = 0; mt < 4; ++mt)
      #pragma unroll
      for (int cc = 0; cc < 2; ++cc) {
        int ct = 2 * mh + cc;
        #pragma unroll
        for (int j = 0; j < 4; ++j)
          Psc[(mt * 16 + rbase + j) * 40 + cc * 16 + rowa] = f2bf(dt_[mt][ct][j]);
      }
    #pragma unroll
    for (int mm = 0; mm < 2; ++mm) {
      int mtm = 2 * mh + mm;
      #pragma unroll
      for (int ct = 0; ct < 4; ++ct)
        #pragma unroll
        for (int p = 0; p < 2; ++p) {
          unsigned u = vp[mtm][ct][p];
          int m_ = mm * 16 + rbase + 2 * p;
          int d  = ct * 16 + rowa;
          *(unsigned*)(vTsc + d * 40 + m_) = u;  // two adjacent m' -> one b32 write
        }
    }
    bf16x8 ap[4];
    #pragma unroll
    for (int mt = 0; mt < 4; ++mt)
      ap[mt] = *(const bf16x8*)(Psc + (mt * 16 + rowa) * 40 + kgrp * 8);
    #pragma unroll
    for (int dtt = 0; dtt < 4; ++dtt) {
      bf16x8 bv = *(const bf16x8*)(vTsc + (dtt * 16 + rowa) * 40 + kgrp * 8);
      #pragma unroll
      for (int mt = 0; mt < 4; ++mt)
        oat[mt][dtt] = __builtin_amdgcn_mfma_f32_16x16x32_bf16(ap[mt], bv, oat[mt][dtt], 0, 0, 0);
    }
  }

  __syncthreads();  // all waves done with private scratch before att_out overlay

  // normalize + stage att_out (cols [wave*64, wave*64+64)) into lds0
  #pragma unroll
  for (int mt = 0; mt < 4; ++mt)
    #pragma unroll
    for (int j = 0; j < 4; ++j) {
      float inv = 1.f / rsum[mt][j];
      #pragma unroll
      for (int dtt = 0; dtt < 4; ++dtt)
        lds0[(mt * 16 + rbase + j) * 520 + wave * 64 + dtt * 16 + rowa] =
            f2bf(oat[mt][dtt][j] * inv);
    }
  __syncthreads();

  // ---------------- GEMM2: out2 = att_out @ w_out^T + b_out ----------
  f32x4 a2[4][4];
  #pragma unroll
  for (int i = 0; i < 4; ++i)
    #pragma unroll
    for (int j = 0; j < 4; ++j) a2[i][j] = (f32x4){0.f, 0.f, 0.f, 0.f};
  for (int ks = 0; ks < 16; ++ks) {
    bf16x8 a[4];
    #pragma unroll
    for (int mt = 0; mt < 4; ++mt)
      a[mt] = *(const bf16x8*)(lds0 + (mt * 16 + rowa) * 520 + ks * 32 + kgrp * 8);
    #pragma unroll
    for (int nt = 0; nt < 4; ++nt) {
      bf16x8 bw = *(const bf16x8*)(wo + (size_t)(wave * 64 + nt * 16 + rowa) * 512 + ks * 32 + kgrp * 8);
      #pragma unroll
      for (int mt = 0; mt < 4; ++mt)
        a2[mt][nt] = __builtin_amdgcn_mfma_f32_16x16x32_bf16(a[mt], bw, a2[mt][nt], 0, 0, 0);
    }
  }

  float bias[4];
  #pragma unroll
  for (int nt = 0; nt < 4; ++nt) bias[nt] = b_out[wave * 64 + nt * 16 + rowa];

  if (use_ws) {
    // value (l = mt*16+kgrp*4+j, o = wave*64+nt*16+rowa) -> ws[bid][o][l]
    // j spans 4 consecutive l -> float4 stores, 16 full 64B lines per wave-instr
    float* wbase = wsout + (size_t)bid * 32768;
    #pragma unroll
    for (int mt = 0; mt < 4; ++mt)
      #pragma unroll
      for (int nt = 0; nt < 4; ++nt) {
        float4 v;
        v.x = a2[mt][nt][0] + bias[nt];
        v.y = a2[mt][nt][1] + bias[nt];
        v.z = a2[mt][nt][2] + bias[nt];
        v.w = a2[mt][nt][3] + bias[nt];
        *(float4*)(wbase + (wave * 64 + nt * 16 + rowa) * 64 + mt * 16 + kgrp * 4) = v;
      }
  } else {
    // fallback: uncoalesced atomic scatter (correct but slow)
    #pragma unroll
    for (int mt = 0; mt < 4; ++mt)
      #pragma unroll
      for (int j = 0; j < 4; ++j) {
        int l = mt * 16 + rbase + j;
        #pragma unroll
        for (int nt = 0; nt < 4; ++nt) {
          int o = wave * 64 + nt * 16 + rowa;
          float val = a2[mt][nt][j] + bias[nt];
          int ch = l * 8 + (o >> 6);
          int p  = o & 63;
          int gh = i0 + (p >> 3);
          int gw = j0 + (p & 7);
          atomicAdd(res + (((size_t)(b * 64 + gh)) * 64 + gw) * 512 + ch, val);
        }
      }
  }
}

extern "C" void kernel_launch(void* const* d_in, const int* in_sizes, int n_in,
                              void* d_out, int out_size, void* d_ws, size_t ws_size,
                              hipStream_t stream) {
  const float* x      = (const float*)d_in[0];
  const float* w_qkv  = (const float*)d_in[1];
  const float* w_out  = (const float*)d_in[2];
  const float* b_out  = (const float*)d_in[3];
  // d_in[4], d_in[5] (rel_h, rel_w): per-query-row constant bias is softmax-invariant -> unused
  float* res = (float*)d_out;
  unsigned short* wbf = (unsigned short*)d_ws;  // [0,2MB) weights bf16
  float* wsf = (float*)((char*)d_ws + (2u << 20));  // per-window outputs, 236MB

  const size_t needed = (2u << 20) + (size_t)NWIN * 32768 * sizeof(float);
  const int use_ws = (ws_size >= needed) ? 1 : 0;

  if (!use_ws) hipMemsetAsync(d_out, 0, (size_t)out_size * sizeof(float), stream);
  convert_weights<<<1024, 256, 0, stream>>>(w_qkv, w_out, wbf);
  swin_kernel<<<NWIN, 512, 0, stream>>>(x, b_out, wbf, wbf + 786432, res, wsf, use_ws);
  if (use_ws) gather_kernel<<<16384, 256, 0, stream>>>(wsf, res);
}

// Round 3
// 1149.840 us; speedup vs baseline: 2.6842x; 2.4580x over previous
//
#include <hip/hip_runtime.h>

#define NHW 15
#define NWIN (8 * NHW * NHW)  // 1800

typedef __bf16 bf16x8 __attribute__((ext_vector_type(8)));
typedef float f32x4 __attribute__((ext_vector_type(4)));
typedef unsigned short u16x8 __attribute__((ext_vector_type(8)));

__device__ __forceinline__ unsigned short f2bf(float f) {
  unsigned x = __float_as_uint(f);
  unsigned r = ((x >> 16) & 1u) + 0x7fffu;  // round-to-nearest-even
  x += r;
  return (unsigned short)(x >> 16);
}

// K-permutation for GEMM1: stored col c' <-> original channel c = 64*(c'%8) + c'/8.
// Applied to BOTH xv staging and w_qkv columns; dot product is invariant.
// w_qkv: dst[o][a*8+e] = wq[o][64*e + a].  w_out: unpermuted.
__global__ void convert_weights(const float* __restrict__ wq,
                                const float* __restrict__ wo,
                                unsigned short* __restrict__ dst) {
  int t = blockIdx.x * 256 + threadIdx.x;
  if (t < 98304) {  // 1536 * 64
    int o = t >> 6, a = t & 63;
    const float* src = wq + (size_t)o * 512 + a;
    u16x8 v;
    #pragma unroll
    for (int e = 0; e < 8; ++e) v[e] = f2bf(src[e * 64]);
    *(u16x8*)(dst + (size_t)o * 512 + a * 8) = v;
  } else {          // w_out: 512*512 / 4 per thread
    int i = (t - 98304) * 4;
    float4 v = *(const float4*)(wo + i);
    ushort4 o4;
    o4.x = f2bf(v.x); o4.y = f2bf(v.y); o4.z = f2bf(v.z); o4.w = f2bf(v.w);
    *(ushort4*)(dst + 786432 + i) = o4;
  }
}

// Sum <=4 overlapping window contributions per output element.
// ws layout per window: [o(512)][l(64)] f32; value (l,o) goes to
// res[b, 4n+(p>>3), 4w+(p&7), l*8+(o>>6)] with p = o&63.
__launch_bounds__(256)
__global__ void gather_kernel(const float* __restrict__ wsf,
                              float* __restrict__ res) {
  int t  = blockIdx.x * 256 + threadIdx.x;  // [0, 4194304) float4s
  int ch4 = (t & 127) << 2;                 // 0..508 step 4
  int r1 = t >> 7;
  int gw = r1 & 63;
  int r2 = r1 >> 6;
  int gh = r2 & 63;
  int b  = r2 >> 6;
  int l   = ch4 >> 3;
  int c70 = ch4 & 7;  // 0 or 4
  int n_lo = (gh >= 8) ? ((gh - 4) >> 2) : 0;
  int n_hi = min(gh >> 2, NHW - 1);
  int w_lo = (gw >= 8) ? ((gw - 4) >> 2) : 0;
  int w_hi = min(gw >> 2, NHW - 1);
  float4 acc = {0.f, 0.f, 0.f, 0.f};
  for (int n = n_lo; n <= n_hi; ++n)
    for (int w = w_lo; w <= w_hi; ++w) {
      const float* base = wsf + ((size_t)((b * NHW + n) * NHW + w)) * 32768;
      int p   = (gh - 4 * n) * 8 + (gw - 4 * w);
      int off = p * 64 + l;
      acc.x += base[(c70 + 0) * 4096 + off];
      acc.y += base[(c70 + 1) * 4096 + off];
      acc.z += base[(c70 + 2) * 4096 + off];
      acc.w += base[(c70 + 3) * 4096 + off];
    }
  *(float4*)(res + ((size_t)t << 2)) = acc;
}

// min-waves=2 -> VGPR cap 256: qp/kp/vp (96) + AGPR acc fit WITHOUT spilling.
// (512,4) in round 2 capped at 128 -> 12 GB of scratch spill traffic. Do not raise.
__launch_bounds__(512, 2)
__global__ void swin_kernel(const float* __restrict__ x,
                            const float* __restrict__ b_out,
                            const unsigned short* __restrict__ wq_all,  // [1536][512] bf16, K-permuted
                            const unsigned short* __restrict__ wo,      // [512][512]  bf16
                            float* __restrict__ res,
                            float* __restrict__ wsout,
                            int use_ws) {
  // single 80KiB region, time-shared:
  //   phase A: xv[64][520] bf16 (66560B), K-permuted cols: c' = pos*8 + e
  //   phase B: 8 x 10240B per-wave attention scratch
  //   phase C: att_out[64][520] bf16
  __shared__ __align__(16) unsigned short lds0[40960];  // 81920 B

  const int tid  = threadIdx.x;
  const int wave = tid >> 6;
  const int ln   = tid & 63;
  const int rowa = ln & 15;   // A-frag row / B-frag col within 16-tile
  const int kgrp = ln >> 4;   // 0..3 : k-subgroup (8 elems each)
  const int rbase = kgrp * 4; // C/D-layout row base within 16-tile

  const int bid = blockIdx.x;
  const int b  = bid / (NHW * NHW);
  const int rm = bid % (NHW * NHW);
  const int n  = rm / NHW;
  const int w  = rm % NHW;
  const int i0 = n * 4, j0 = w * 4;

  // ---------------- stage patch xv (bf16, K-permuted) ----------------
  // xv'[l][pos*8+e] = x[b, i0+pos/8, j0+pos%8, 8l+e]
  // wave = kj, lane = l: read 8 consecutive channels of pixel (r,kj),
  // write one contiguous 16B ds_write_b128 (bank start 4l%32 -> conflict-free).
  {
    const int l_st = ln;
    const int kj_st = wave;
    for (int r = 0; r < 8; ++r) {
      const float* src = x + (((size_t)(b * 64 + i0 + r)) * 64 + j0 + kj_st) * 512 + 8 * l_st;
      float4 v0 = *(const float4*)(src);
      float4 v1 = *(const float4*)(src + 4);
      u16x8 pk;
      pk[0] = f2bf(v0.x); pk[1] = f2bf(v0.y); pk[2] = f2bf(v0.z); pk[3] = f2bf(v0.w);
      pk[4] = f2bf(v1.x); pk[5] = f2bf(v1.y); pk[6] = f2bf(v1.z); pk[7] = f2bf(v1.w);
      *(u16x8*)(lds0 + l_st * 520 + (r * 8 + kj_st) * 8) = pk;
    }
  }
  __syncthreads();

  // ---------------- GEMM1: qkv = xv @ W^T (3 steps; wave owns head `wave`) ----
  unsigned qp[4][4][2], kp[4][4][2], vp[4][4][2];  // packed bf16 pairs (rows 2p,2p+1)
  {
    auto step = [&](int O, unsigned (&dst)[4][4][2]) {
      f32x4 acc[4][4];
      #pragma unroll
      for (int i = 0; i < 4; ++i)
        #pragma unroll
        for (int j = 0; j < 4; ++j) acc[i][j] = (f32x4){0.f, 0.f, 0.f, 0.f};
      for (int ks = 0; ks < 16; ++ks) {
        bf16x8 a[4];
        #pragma unroll
        for (int mt = 0; mt < 4; ++mt)
          a[mt] = *(const bf16x8*)(lds0 + (mt * 16 + rowa) * 520 + ks * 32 + kgrp * 8);
        #pragma unroll
        for (int nt = 0; nt < 4; ++nt) {
          bf16x8 bfr = *(const bf16x8*)(wq_all + (size_t)(O + nt * 16 + rowa) * 512 + ks * 32 + kgrp * 8);
          #pragma unroll
          for (int mt = 0; mt < 4; ++mt)
            acc[mt][nt] = __builtin_amdgcn_mfma_f32_16x16x32_bf16(a[mt], bfr, acc[mt][nt], 0, 0, 0);
        }
      }
      #pragma unroll
      for (int mt = 0; mt < 4; ++mt)
        #pragma unroll
        for (int nt = 0; nt < 4; ++nt)
          #pragma unroll
          for (int p = 0; p < 2; ++p)
            dst[mt][nt][p] = (unsigned)f2bf(acc[mt][nt][2 * p]) |
                             ((unsigned)f2bf(acc[mt][nt][2 * p + 1]) << 16);
    };
    step(wave * 64,        qp);
    step(512 + wave * 64,  kp);
    step(1024 + wave * 64, vp);
  }
  __syncthreads();  // xv dead; per-wave scratch may overlay lds0

  // ---------------- attention: head = wave, all private -------------
  unsigned short* qsc = lds0 + wave * 5120;  // 64 x 40 bf16 rows (80B, 16B aligned)
  unsigned short* ksc = qsc + 2560;

  f32x4 dt_[4][4];
  #pragma unroll
  for (int i = 0; i < 4; ++i)
    #pragma unroll
    for (int j = 0; j < 4; ++j) dt_[i][j] = (f32x4){0.f, 0.f, 0.f, 0.f};

  #pragma unroll
  for (int h2 = 0; h2 < 2; ++h2) {  // d-half of K=64
    #pragma unroll
    for (int mt = 0; mt < 4; ++mt)
      #pragma unroll
      for (int cc = 0; cc < 2; ++cc) {
        int ct = 2 * h2 + cc;
        #pragma unroll
        for (int p = 0; p < 2; ++p) {
          unsigned uq = qp[mt][ct][p];
          unsigned uk = kp[mt][ct][p];
          int rr = mt * 16 + rbase + 2 * p;
          int dd = cc * 16 + rowa;
          qsc[rr * 40 + dd]       = (unsigned short)uq;
          qsc[(rr + 1) * 40 + dd] = (unsigned short)(uq >> 16);
          ksc[rr * 40 + dd]       = (unsigned short)uk;
          ksc[(rr + 1) * 40 + dd] = (unsigned short)(uk >> 16);
        }
      }
    bf16x8 aq[4];
    #pragma unroll
    for (int mt = 0; mt < 4; ++mt)
      aq[mt] = *(const bf16x8*)(qsc + (mt * 16 + rowa) * 40 + kgrp * 8);
    #pragma unroll
    for (int nt = 0; nt < 4; ++nt) {
      bf16x8 bk = *(const bf16x8*)(ksc + (nt * 16 + rowa) * 40 + kgrp * 8);
      #pragma unroll
      for (int mt = 0; mt < 4; ++mt)
        dt_[mt][nt] = __builtin_amdgcn_mfma_f32_16x16x32_bf16(aq[mt], bk, dt_[mt][nt], 0, 0, 0);
    }
  }

  // softmax (scale = hd^-0.5 = 1/8); per-row constant bias drops out exactly
  const float SC = 0.125f * 1.44269504088896f;
  float rsum[4][4];
  #pragma unroll
  for (int mt = 0; mt < 4; ++mt)
    #pragma unroll
    for (int j = 0; j < 4; ++j) {
      float m = dt_[mt][0][j];
      #pragma unroll
      for (int nt = 1; nt < 4; ++nt) m = fmaxf(m, dt_[mt][nt][j]);
      #pragma unroll
      for (int s = 1; s < 16; s <<= 1) m = fmaxf(m, __shfl_xor(m, s, 64));
      float sum = 0.f;
      #pragma unroll
      for (int nt = 0; nt < 4; ++nt) {
        float p = exp2f((dt_[mt][nt][j] - m) * SC);
        dt_[mt][nt][j] = p;
        sum += p;
      }
      #pragma unroll
      for (int s = 1; s < 16; s <<= 1) sum += __shfl_xor(sum, s, 64);
      rsum[mt][j] = sum;
    }

  // PV: out_h = P @ v  (stage P and v^T per m-half; same-wave scratch reuse)
  unsigned short* Psc  = qsc;
  unsigned short* vTsc = ksc;
  f32x4 oat[4][4];
  #pragma unroll
  for (int i = 0; i < 4; ++i)
    #pragma unroll
    for (int j = 0; j < 4; ++j) oat[i][j] = (f32x4){0.f, 0.f, 0.f, 0.f};

  #pragma unroll
  for (int mh = 0; mh < 2; ++mh) {
    #pragma unroll
    for (int mt = 0; mt < 4; ++mt)
      #pragma unroll
      for (int cc = 0; cc < 2; ++cc) {
        int ct = 2 * mh + cc;
        #pragma unroll
        for (int j = 0; j < 4; ++j)
          Psc[(mt * 16 + rbase + j) * 40 + cc * 16 + rowa] = f2bf(dt_[mt][ct][j]);
      }
    #pragma unroll
    for (int mm = 0; mm < 2; ++mm) {
      int mtm = 2 * mh + mm;
      #pragma unroll
      for (int ct = 0; ct < 4; ++ct)
        #pragma unroll
        for (int p = 0; p < 2; ++p) {
          unsigned u = vp[mtm][ct][p];
          int m_ = mm * 16 + rbase + 2 * p;
          int d  = ct * 16 + rowa;
          *(unsigned*)(vTsc + d * 40 + m_) = u;  // two adjacent m' -> one b32 write
        }
    }
    bf16x8 ap[4];
    #pragma unroll
    for (int mt = 0; mt < 4; ++mt)
      ap[mt] = *(const bf16x8*)(Psc + (mt * 16 + rowa) * 40 + kgrp * 8);
    #pragma unroll
    for (int dtt = 0; dtt < 4; ++dtt) {
      bf16x8 bv = *(const bf16x8*)(vTsc + (dtt * 16 + rowa) * 40 + kgrp * 8);
      #pragma unroll
      for (int mt = 0; mt < 4; ++mt)
        oat[mt][dtt] = __builtin_amdgcn_mfma_f32_16x16x32_bf16(ap[mt], bv, oat[mt][dtt], 0, 0, 0);
    }
  }

  __syncthreads();  // all waves done with private scratch before att_out overlay

  // normalize + stage att_out (cols [wave*64, wave*64+64)) into lds0
  #pragma unroll
  for (int mt = 0; mt < 4; ++mt)
    #pragma unroll
    for (int j = 0; j < 4; ++j) {
      float inv = 1.f / rsum[mt][j];
      #pragma unroll
      for (int dtt = 0; dtt < 4; ++dtt)
        lds0[(mt * 16 + rbase + j) * 520 + wave * 64 + dtt * 16 + rowa] =
            f2bf(oat[mt][dtt][j] * inv);
    }
  __syncthreads();

  // ---------------- GEMM2: out2 = att_out @ w_out^T + b_out ----------
  f32x4 a2[4][4];
  #pragma unroll
  for (int i = 0; i < 4; ++i)
    #pragma unroll
    for (int j = 0; j < 4; ++j) a2[i][j] = (f32x4){0.f, 0.f, 0.f, 0.f};
  for (int ks = 0; ks < 16; ++ks) {
    bf16x8 a[4];
    #pragma unroll
    for (int mt = 0; mt < 4; ++mt)
      a[mt] = *(const bf16x8*)(lds0 + (mt * 16 + rowa) * 520 + ks * 32 + kgrp * 8);
    #pragma unroll
    for (int nt = 0; nt < 4; ++nt) {
      bf16x8 bw = *(const bf16x8*)(wo + (size_t)(wave * 64 + nt * 16 + rowa) * 512 + ks * 32 + kgrp * 8);
      #pragma unroll
      for (int mt = 0; mt < 4; ++mt)
        a2[mt][nt] = __builtin_amdgcn_mfma_f32_16x16x32_bf16(a[mt], bw, a2[mt][nt], 0, 0, 0);
    }
  }

  float bias[4];
  #pragma unroll
  for (int nt = 0; nt < 4; ++nt) bias[nt] = b_out[wave * 64 + nt * 16 + rowa];

  if (use_ws) {
    // value (l = mt*16+kgrp*4+j, o = wave*64+nt*16+rowa) -> ws[bid][o][l]
    float* wbase = wsout + (size_t)bid * 32768;
    #pragma unroll
    for (int mt = 0; mt < 4; ++mt)
      #pragma unroll
      for (int nt = 0; nt < 4; ++nt) {
        float4 v;
        v.x = a2[mt][nt][0] + bias[nt];
        v.y = a2[mt][nt][1] + bias[nt];
        v.z = a2[mt][nt][2] + bias[nt];
        v.w = a2[mt][nt][3] + bias[nt];
        *(float4*)(wbase + (wave * 64 + nt * 16 + rowa) * 64 + mt * 16 + kgrp * 4) = v;
      }
  } else {
    // fallback: uncoalesced atomic scatter (correct but slow)
    #pragma unroll
    for (int mt = 0; mt < 4; ++mt)
      #pragma unroll
      for (int j = 0; j < 4; ++j) {
        int l = mt * 16 + rbase + j;
        #pragma unroll
        for (int nt = 0; nt < 4; ++nt) {
          int o = wave * 64 + nt * 16 + rowa;
          float val = a2[mt][nt][j] + bias[nt];
          int ch = l * 8 + (o >> 6);
          int p  = o & 63;
          int gh = i0 + (p >> 3);
          int gw = j0 + (p & 7);
          atomicAdd(res + (((size_t)(b * 64 + gh)) * 64 + gw) * 512 + ch, val);
        }
      }
  }
}

extern "C" void kernel_launch(void* const* d_in, const int* in_sizes, int n_in,
                              void* d_out, int out_size, void* d_ws, size_t ws_size,
                              hipStream_t stream) {
  const float* x      = (const float*)d_in[0];
  const float* w_qkv  = (const float*)d_in[1];
  const float* w_out  = (const float*)d_in[2];
  const float* b_out  = (const float*)d_in[3];
  // d_in[4], d_in[5] (rel_h, rel_w): per-query-row constant bias is softmax-invariant -> unused
  float* res = (float*)d_out;
  unsigned short* wbf = (unsigned short*)d_ws;  // [0,2MB) weights bf16
  float* wsf = (float*)((char*)d_ws + (2u << 20));  // per-window outputs, 236MB

  const size_t needed = (2u << 20) + (size_t)NWIN * 32768 * sizeof(float);
  const int use_ws = (ws_size >= needed) ? 1 : 0;

  if (!use_ws) hipMemsetAsync(d_out, 0, (size_t)out_size * sizeof(float), stream);
  convert_weights<<<640, 256, 0, stream>>>(w_qkv, w_out, wbf);
  swin_kernel<<<NWIN, 512, 0, stream>>>(x, b_out, wbf, wbf + 786432, res, wsf, use_ws);
  if (use_ws) gather_kernel<<<16384, 256, 0, stream>>>(wsf, res);
}